// Round 7
// baseline (350.322 us; speedup 1.0000x reference)
//
#include <hip/hip_runtime.h>
#include <hip/hip_bf16.h>

#define IN_SIZE 4096
#define OUT_SIZE 4096
#define BATCH 4096

// 512 source blocks x 8192 entries; 1024 cells of 4 W-rows.
// One-pass reservation scatter: per-cell capacity segments (8192 entries/cell)
// living in d_out (C is dead until the GEMM epilogue rewrites all of it).
#define NBLK 512
#define CHUNK 8192
#define NCELL 1024
#define CELLCAP 8192

typedef __bf16 bf16x8 __attribute__((ext_vector_type(8)));
typedef float f32x4 __attribute__((ext_vector_type(4)));

// ------------------------------------------------------- K0: zero cellcnt
__global__ __launch_bounds__(256) void zero_kernel(int* __restrict__ cellcnt) {
    cellcnt[blockIdx.x * 256 + threadIdx.x & 1023] = 0;   // 4 blocks x 256
}

// ---------------- K1: stage iout in LDS, hist, reserve global ranges, scatter
__global__ __launch_bounds__(512) void scatres_kernel(const float* __restrict__ vals,
                                                      const int* __restrict__ iin,
                                                      const int* __restrict__ iout,
                                                      int* __restrict__ cellcnt,
                                                      uint2* __restrict__ bkt, int nnz) {
    __shared__ int sout[CHUNK];      // 32 KB staged iout
    __shared__ int hist[NCELL];      // 4 KB (then used as countdown)
    __shared__ int gbase[NCELL];     // 4 KB
    const int b = blockIdx.x, tid = threadIdx.x;
    const int base = b * CHUNK;

    for (int c = tid; c < NCELL; c += 512) hist[c] = 0;
    __syncthreads();

    const int4* io4 = (const int4*)(iout + base);
    for (int i = tid; i < CHUNK / 4; i += 512) {
        if (base + i * 4 + 3 < nnz) {
            const int4 o = io4[i];
            ((int4*)sout)[i] = o;
            atomicAdd(&hist[o.x >> 2], 1);
            atomicAdd(&hist[o.y >> 2], 1);
            atomicAdd(&hist[o.z >> 2], 1);
            atomicAdd(&hist[o.w >> 2], 1);
        } else {
            for (int j = 0; j < 4; ++j) {
                const int k = base + i * 4 + j;
                if (k < nnz) {
                    const int o = iout[k];
                    sout[i * 4 + j] = o;
                    atomicAdd(&hist[o >> 2], 1);
                }
            }
        }
    }
    __syncthreads();

    // reserve one contiguous run per non-empty cell
    for (int c = tid; c < NCELL; c += 512)
        gbase[c] = hist[c] ? atomicAdd(&cellcnt[c], hist[c]) : 0;
    __syncthreads();

    // scatter: entry slot = cell*CELLCAP + gbase[cell] + (countdown-1)
    const float4* v4 = (const float4*)(vals + base);
    const int4*   a4 = (const int4*)(iin + base);
    for (int i = tid; i < CHUNK / 4; i += 512) {
        if (base + i * 4 + 3 < nnz) {
            const float4 v = v4[i];
            const int4   a = a4[i];
            const int4   o = ((const int4*)sout)[i];
            int c, l; uint2 e;
            c = o.x >> 2; l = atomicSub(&hist[c], 1) - 1;
            e.x = __builtin_bit_cast(unsigned, v.x); e.y = (unsigned)(((o.x & 3) << 12) | a.x);
            bkt[(size_t)c * CELLCAP + gbase[c] + l] = e;
            c = o.y >> 2; l = atomicSub(&hist[c], 1) - 1;
            e.x = __builtin_bit_cast(unsigned, v.y); e.y = (unsigned)(((o.y & 3) << 12) | a.y);
            bkt[(size_t)c * CELLCAP + gbase[c] + l] = e;
            c = o.z >> 2; l = atomicSub(&hist[c], 1) - 1;
            e.x = __builtin_bit_cast(unsigned, v.z); e.y = (unsigned)(((o.z & 3) << 12) | a.z);
            bkt[(size_t)c * CELLCAP + gbase[c] + l] = e;
            c = o.w >> 2; l = atomicSub(&hist[c], 1) - 1;
            e.x = __builtin_bit_cast(unsigned, v.w); e.y = (unsigned)(((o.w & 3) << 12) | a.w);
            bkt[(size_t)c * CELLCAP + gbase[c] + l] = e;
        } else {
            for (int j = 0; j < 4; ++j) {
                const int k = base + i * 4 + j;
                if (k < nnz) {
                    const int o = sout[i * 4 + j];
                    const int c = o >> 2;
                    const int l = atomicSub(&hist[c], 1) - 1;
                    uint2 e;
                    e.x = __builtin_bit_cast(unsigned, vals[k]);
                    e.y = (unsigned)(((o & 3) << 12) | iin[k]);
                    bkt[(size_t)c * CELLCAP + gbase[c] + l] = e;
                }
            }
        }
    }
}

// ---- K2: per-cell accumulate (packed prefix, LDS fp32) -> bf16 W (+x cvt)
__global__ __launch_bounds__(512) void accum_kernel(const uint2* __restrict__ bkt,
                                                    const int* __restrict__ cellcnt,
                                                    __bf16* __restrict__ W,
                                                    const f32x4* __restrict__ xin,
                                                    bf16x8* __restrict__ xout) {
    __shared__ float acc[4 * 4096];     // 64 KB
    const int cell = blockIdx.x, tid = threadIdx.x;
    for (int t = tid; t < 4 * 4096; t += 512) acc[t] = 0.f;
    int n = cellcnt[cell];
    if (n > CELLCAP) n = CELLCAP;
    __syncthreads();

    const uint2* seg = bkt + (size_t)cell * CELLCAP;
    for (int s = tid; s < n; s += 512) {
        const uint2 e = seg[s];
        atomicAdd(&acc[((e.y >> 12) & 3u) * 4096 + (e.y & 0xFFFu)],
                  __builtin_bit_cast(float, e.x));
    }
    __syncthreads();

    bf16x8* out = (bf16x8*)(W + (size_t)cell * 4 * 4096);
    for (int t = tid; t < 2048; t += 512) {
        bf16x8 o;
#pragma unroll
        for (int j = 0; j < 8; ++j) o[j] = (__bf16)acc[t * 8 + j];
        out[t] = o;
    }

    // fused x -> bf16 (2048 vec8 per block; 1024 blocks cover 16.7M elems)
    const int xbase = blockIdx.x * 2048;
    for (int t = tid; t < 2048; t += 512) {
        const int idx = xbase + t;
        const f32x4 a = xin[2 * idx];
        const f32x4 bq = xin[2 * idx + 1];
        bf16x8 o;
        o[0] = (__bf16)a[0];  o[1] = (__bf16)a[1];  o[2] = (__bf16)a[2];  o[3] = (__bf16)a[3];
        o[4] = (__bf16)bq[0]; o[5] = (__bf16)bq[1]; o[6] = (__bf16)bq[2]; o[7] = (__bf16)bq[3];
        xout[idx] = o;
    }
}

// ----------------------------------------------------------------- GEMM
// C[M][N] = A[M][K] * B[N][K]^T, all 4096, A/B bf16 row-major, C fp32.
// 256x256 tile, BK=32, 8 waves (2M x 4N), 8x4 16x16x32-bf16 frags/wave.
// Round-7: register fragment double-buffering so every ds_read issues UNDER
// an MFMA cluster (round-5 model: ds 768cy + MFMA 1242cy were serialized),
// within the proven 4-buffer 128 KB LDS footprint (round-6's 6-buf = 192 KB
// exceeded LDS).  Stage horizon t+3, steady vmcnt(4): at end of iter t-1,
// issued <= stage(t+2), vmcnt(4) => tiles <= t+1 landed => iter t's mid-iter
// prefetch of tile t+1 is safe; stage(t+3) has ~2 iters before first read.
// ONE barrier per K-tile.  Buffer(t&3) x regset(t&1) => period-4 unroll.
// Same zero-conflict XOR swizzle / XCD swizzle / epilogue as rounds 2-5.

#define GLL(SRC, DST)                                                         \
    __builtin_amdgcn_global_load_lds(                                         \
        (const __attribute__((address_space(1))) void*)(SRC),                 \
        (__attribute__((address_space(3))) void*)(DST), 16, 0, 0)

#define STAGE_AB(T, BUF)                                                      \
  do {                                                                        \
    const __bf16* sa_ = gA0 + (size_t)(T) * 32;                               \
    __bf16* da_ = &smem[(BUF) * 16384 + tid * 8];                             \
    GLL(sa_, da_);                                                            \
    GLL(sa_ + (size_t)524288, da_ + 4096);                                    \
    const __bf16* sb_ = gB0 + (size_t)(T) * 32;                               \
    __bf16* db_ = &smem[(BUF) * 16384 + 8192 + tid * 8];                      \
    GLL(sb_, db_);                                                            \
    GLL(sb_ + (size_t)524288, db_ + 4096);                                    \
  } while (0)

#define VMW8  asm volatile("s_waitcnt vmcnt(8)" ::: "memory")
#define VMW4  asm volatile("s_waitcnt vmcnt(4)" ::: "memory")
#define VMW0  asm volatile("s_waitcnt vmcnt(0)" ::: "memory")
#define VMWN  ((void)0)
#define LGKM0 asm volatile("s_waitcnt lgkmcnt(0)" ::: "memory")

#define LBFR(D, BUF)                                                          \
    _Pragma("unroll") for (int j_ = 0; j_ < 4; ++j_)                          \
        D[j_] = *(const bf16x8*)(smem + (BUF) * 16384 + offB[j_])
#define LA03(D, BUF)                                                          \
    _Pragma("unroll") for (int i_ = 0; i_ < 4; ++i_)                          \
        D[i_] = *(const bf16x8*)(smem + (BUF) * 16384 + offA[i_])
#define LA47(BUF)                                                             \
    _Pragma("unroll") for (int i_ = 0; i_ < 4; ++i_)                          \
        af47[i_] = *(const bf16x8*)(smem + (BUF) * 16384 + offA[4 + i_])

#define MFMA_C1(CA, CB)                                                       \
    _Pragma("unroll") for (int i_ = 0; i_ < 4; ++i_)                          \
        _Pragma("unroll") for (int j_ = 0; j_ < 4; ++j_)                      \
            acc[i_][j_] = __builtin_amdgcn_mfma_f32_16x16x32_bf16(            \
                CA[i_], CB[j_], acc[i_][j_], 0, 0, 0)
#define MFMA_C2(CB)                                                           \
    _Pragma("unroll") for (int i_ = 0; i_ < 4; ++i_)                          \
        _Pragma("unroll") for (int j_ = 0; j_ < 4; ++j_)                      \
            acc[4 + i_][j_] = __builtin_amdgcn_mfma_f32_16x16x32_bf16(        \
                af47[i_], CB[j_], acc[4 + i_][j_], 0, 0, 0)

// one K-tile: stage(T+3) | LA47(T) under MFMA1 | next-set frags under MFMA2
#define ITER(T, BUFC, BUFN, CB, CA, NB, NA, DOSTAGE, SBUF, VMW, DOBAR)        \
  do {                                                                        \
    if (DOSTAGE) STAGE_AB((T) + 3, SBUF);                                     \
    LA47(BUFC);                                                               \
    __builtin_amdgcn_s_setprio(1);                                            \
    MFMA_C1(CA, CB);                                                          \
    __builtin_amdgcn_s_setprio(0);                                            \
    LBFR(NB, BUFN);                                                           \
    LA03(NA, BUFN);                                                           \
    __builtin_amdgcn_s_setprio(1);                                            \
    MFMA_C2(CB);                                                              \
    __builtin_amdgcn_s_setprio(0);                                            \
    LGKM0;                                                                    \
    VMW;                                                                      \
    if (DOBAR) __builtin_amdgcn_s_barrier();                                  \
  } while (0)

__global__ __launch_bounds__(512, 2) void gemm_bt_kernel(
    const __bf16* __restrict__ A,
    const __bf16* __restrict__ B,
    float* __restrict__ C) {
    __shared__ __bf16 smem[4 * 16384];   // 128 KB: 4 bufs x (A 8192 | B 8192)

    const int tid   = threadIdx.x;
    const int lane  = tid & 63;
    const int wv    = tid >> 6;
    const int wm    = wv >> 2;           // 0..1  -> 128 M-rows each
    const int wn    = wv & 3;            // 0..3  -> 64 N-cols each
    const int row16 = lane & 15;
    const int quad  = lane >> 4;

    // bijective XCD swizzle: 256 blocks, 8 XCDs, 32 contiguous tiles/XCD
    const int swz = (blockIdx.x & 7) * 32 + (blockIdx.x >> 3);
    const int bm  = (swz >> 4) * 256;
    const int bn  = (swz & 15) * 256;

    // staging: 512 thr x 16B = 8 KB = 128 rows of 64 B; 2 issues per matrix.
    // slot p holds pre-swizzle chunk q = p ^ ((row>>1)&3)  (inverse == itself)
    const int sr = tid >> 2;                       // local row 0..127
    const int sq = (tid & 3) ^ ((sr >> 1) & 3);    // source 16B-chunk
    const __bf16* gA0 = A + (size_t)(bm + sr) * 4096 + sq * 8;
    const __bf16* gB0 = B + (size_t)(bn + sr) * 4096 + sq * 8;

    // ds_read element offsets (per-lane, constant across tiles)
    int offA[8], offB[4];
#pragma unroll
    for (int i = 0; i < 8; ++i) {
        const int ra = wm * 128 + i * 16 + row16;
        offA[i] = ra * 32 + ((quad ^ ((ra >> 1) & 3)) * 8);
    }
#pragma unroll
    for (int j = 0; j < 4; ++j) {
        const int rb = wn * 64 + j * 16 + row16;
        offB[j] = 8192 + rb * 32 + ((quad ^ ((rb >> 1) & 3)) * 8);
    }

    f32x4  acc[8][4] = {};
    bf16x8 bfr0[4], a0_[4], bfr1[4], a1_[4], af47[4];

    // prologue: stage tiles 0..2 into bufs 0..2; wait tiles 0,1; preload set0
    STAGE_AB(0, 0); STAGE_AB(1, 1); STAGE_AB(2, 2);
    VMW4;                                   // tiles 0,1 landed (tile 2 in flight)
    __builtin_amdgcn_s_barrier();
    LBFR(bfr0, 0);
    LA03(a0_, 0);

    // main: 31 chunks x 4 iters = tiles 0..123 (buffer %4 compile-time)
    for (int c = 0; c < 31; ++c) {
        const int tb = c * 4;
        ITER(tb + 0, 0, 1, bfr0, a0_, bfr1, a1_, 1, 3, VMW4, 1);
        ITER(tb + 1, 1, 2, bfr1, a1_, bfr0, a0_, 1, 0, VMW4, 1);
        ITER(tb + 2, 2, 3, bfr0, a0_, bfr1, a1_, 1, 1, VMW4, 1);
        ITER(tb + 3, 3, 0, bfr1, a1_, bfr0, a0_, 1, 2, VMW4, 1);
    }
    // tail: tiles 124..127 (last stage = tile 127 at iter 124; drain waits)
    ITER(124, 0, 1, bfr0, a0_, bfr1, a1_, 1, 3, VMW4, 1);
    ITER(125, 1, 2, bfr1, a1_, bfr0, a0_, 0, 0, VMW0, 1);
    ITER(126, 2, 3, bfr0, a0_, bfr1, a1_, 0, 0, VMWN, 0);
    // iter 127: MFMA only (set1 frags loaded at iter 126; af47 from buf 3)
    LA47(3);
    __builtin_amdgcn_s_setprio(1);
    MFMA_C1(a1_, bfr1);
    MFMA_C2(bfr1);
    __builtin_amdgcn_s_setprio(0);

#pragma unroll
    for (int i = 0; i < 8; ++i) {
        const int rbase = bm + wm * 128 + i * 16 + quad * 4;
#pragma unroll
        for (int j = 0; j < 4; ++j) {
            const int col = bn + wn * 64 + j * 16 + row16;
#pragma unroll
            for (int r = 0; r < 4; ++r)
                C[(size_t)(rbase + r) * 4096 + col] = acc[i][j][r];
        }
    }
}

extern "C" void kernel_launch(void* const* d_in, const int* in_sizes, int n_in,
                              void* d_out, int out_size, void* d_ws, size_t ws_size,
                              hipStream_t stream) {
    const float* x    = (const float*)d_in[0];
    const float* vals = (const float*)d_in[1];
    const int*   iin  = (const int*)d_in[2];
    const int*   iout = (const int*)d_in[3];
    float*       C    = (float*)d_out;
    const int    nnz  = in_sizes[1];

    // workspace: Wb 32MB | Xb 32MB | cellcnt 4KB  = 64 MB; bkt lives in d_out
    char*   ws      = (char*)d_ws;
    __bf16* Wb      = (__bf16*)ws;
    __bf16* Xb      = (__bf16*)(ws + ((size_t)32 << 20));
    int*    cellcnt = (int*)(ws + ((size_t)64 << 20));
    uint2*  bkt     = (uint2*)d_out;   // 1024 cells x 8192 cap x 8 B = 64 MB

    zero_kernel<<<4, 256, 0, stream>>>(cellcnt);
    scatres_kernel<<<NBLK, 512, 0, stream>>>(vals, iin, iout, cellcnt, bkt, nnz);
    accum_kernel<<<NCELL, 512, 0, stream>>>(bkt, cellcnt, Wb, (const f32x4*)x, (bf16x8*)Xb);
    gemm_bt_kernel<<<256, 512, 0, stream>>>(Xb, Wb, C);
}

// Round 8
// 337.159 us; speedup vs baseline: 1.0390x; 1.0390x over previous
//
#include <hip/hip_runtime.h>
#include <hip/hip_bf16.h>

#define IN_SIZE 4096
#define OUT_SIZE 4096
#define BATCH 4096

// 512 source blocks x 8192 entries; 1024 cells of 4 W-rows.
// One-pass reservation scatter: per-cell capacity segments (8192 entries/cell)
// living in d_out (C is dead until the GEMM epilogue rewrites all of it).
#define NBLK 512
#define CHUNK 8192
#define NCELL 1024
#define CELLCAP 8192

typedef __bf16 bf16x8 __attribute__((ext_vector_type(8)));
typedef float f32x4 __attribute__((ext_vector_type(4)));

// ------------------------------------------------------- K0: zero cellcnt
__global__ __launch_bounds__(256) void zero_kernel(int* __restrict__ cellcnt) {
    cellcnt[blockIdx.x * 256 + threadIdx.x & 1023] = 0;   // 4 blocks x 256
}

// ---------------- K1: stage iout in LDS, hist, reserve global ranges, scatter
__global__ __launch_bounds__(512) void scatres_kernel(const float* __restrict__ vals,
                                                      const int* __restrict__ iin,
                                                      const int* __restrict__ iout,
                                                      int* __restrict__ cellcnt,
                                                      uint2* __restrict__ bkt, int nnz) {
    __shared__ int sout[CHUNK];      // 32 KB staged iout
    __shared__ int hist[NCELL];      // 4 KB (then used as countdown)
    __shared__ int gbase[NCELL];     // 4 KB
    const int b = blockIdx.x, tid = threadIdx.x;
    const int base = b * CHUNK;

    for (int c = tid; c < NCELL; c += 512) hist[c] = 0;
    __syncthreads();

    const int4* io4 = (const int4*)(iout + base);
    for (int i = tid; i < CHUNK / 4; i += 512) {
        if (base + i * 4 + 3 < nnz) {
            const int4 o = io4[i];
            ((int4*)sout)[i] = o;
            atomicAdd(&hist[o.x >> 2], 1);
            atomicAdd(&hist[o.y >> 2], 1);
            atomicAdd(&hist[o.z >> 2], 1);
            atomicAdd(&hist[o.w >> 2], 1);
        } else {
            for (int j = 0; j < 4; ++j) {
                const int k = base + i * 4 + j;
                if (k < nnz) {
                    const int o = iout[k];
                    sout[i * 4 + j] = o;
                    atomicAdd(&hist[o >> 2], 1);
                }
            }
        }
    }
    __syncthreads();

    // reserve one contiguous run per non-empty cell
    for (int c = tid; c < NCELL; c += 512)
        gbase[c] = hist[c] ? atomicAdd(&cellcnt[c], hist[c]) : 0;
    __syncthreads();

    // scatter: entry slot = cell*CELLCAP + gbase[cell] + (countdown-1)
    const float4* v4 = (const float4*)(vals + base);
    const int4*   a4 = (const int4*)(iin + base);
    for (int i = tid; i < CHUNK / 4; i += 512) {
        if (base + i * 4 + 3 < nnz) {
            const float4 v = v4[i];
            const int4   a = a4[i];
            const int4   o = ((const int4*)sout)[i];
            int c, l; uint2 e;
            c = o.x >> 2; l = atomicSub(&hist[c], 1) - 1;
            e.x = __builtin_bit_cast(unsigned, v.x); e.y = (unsigned)(((o.x & 3) << 12) | a.x);
            bkt[(size_t)c * CELLCAP + gbase[c] + l] = e;
            c = o.y >> 2; l = atomicSub(&hist[c], 1) - 1;
            e.x = __builtin_bit_cast(unsigned, v.y); e.y = (unsigned)(((o.y & 3) << 12) | a.y);
            bkt[(size_t)c * CELLCAP + gbase[c] + l] = e;
            c = o.z >> 2; l = atomicSub(&hist[c], 1) - 1;
            e.x = __builtin_bit_cast(unsigned, v.z); e.y = (unsigned)(((o.z & 3) << 12) | a.z);
            bkt[(size_t)c * CELLCAP + gbase[c] + l] = e;
            c = o.w >> 2; l = atomicSub(&hist[c], 1) - 1;
            e.x = __builtin_bit_cast(unsigned, v.w); e.y = (unsigned)(((o.w & 3) << 12) | a.w);
            bkt[(size_t)c * CELLCAP + gbase[c] + l] = e;
        } else {
            for (int j = 0; j < 4; ++j) {
                const int k = base + i * 4 + j;
                if (k < nnz) {
                    const int o = sout[i * 4 + j];
                    const int c = o >> 2;
                    const int l = atomicSub(&hist[c], 1) - 1;
                    uint2 e;
                    e.x = __builtin_bit_cast(unsigned, vals[k]);
                    e.y = (unsigned)(((o & 3) << 12) | iin[k]);
                    bkt[(size_t)c * CELLCAP + gbase[c] + l] = e;
                }
            }
        }
    }
}

// ---- K2: per-cell accumulate (packed prefix, LDS fp32) -> bf16 W (+x cvt)
__global__ __launch_bounds__(512) void accum_kernel(const uint2* __restrict__ bkt,
                                                    const int* __restrict__ cellcnt,
                                                    __bf16* __restrict__ W,
                                                    const f32x4* __restrict__ xin,
                                                    bf16x8* __restrict__ xout) {
    __shared__ float acc[4 * 4096];     // 64 KB
    const int cell = blockIdx.x, tid = threadIdx.x;
    for (int t = tid; t < 4 * 4096; t += 512) acc[t] = 0.f;
    int n = cellcnt[cell];
    if (n > CELLCAP) n = CELLCAP;
    __syncthreads();

    const uint2* seg = bkt + (size_t)cell * CELLCAP;
    for (int s = tid; s < n; s += 512) {
        const uint2 e = seg[s];
        atomicAdd(&acc[((e.y >> 12) & 3u) * 4096 + (e.y & 0xFFFu)],
                  __builtin_bit_cast(float, e.x));
    }
    __syncthreads();

    bf16x8* out = (bf16x8*)(W + (size_t)cell * 4 * 4096);
    for (int t = tid; t < 2048; t += 512) {
        bf16x8 o;
#pragma unroll
        for (int j = 0; j < 8; ++j) o[j] = (__bf16)acc[t * 8 + j];
        out[t] = o;
    }

    // fused x -> bf16 (2048 vec8 per block; 1024 blocks cover 16.7M elems)
    const int xbase = blockIdx.x * 2048;
    for (int t = tid; t < 2048; t += 512) {
        const int idx = xbase + t;
        const f32x4 a = xin[2 * idx];
        const f32x4 bq = xin[2 * idx + 1];
        bf16x8 o;
        o[0] = (__bf16)a[0];  o[1] = (__bf16)a[1];  o[2] = (__bf16)a[2];  o[3] = (__bf16)a[3];
        o[4] = (__bf16)bq[0]; o[5] = (__bf16)bq[1]; o[6] = (__bf16)bq[2]; o[7] = (__bf16)bq[3];
        xout[idx] = o;
    }
}

// ----------------------------------------------------------------- GEMM
// C[M][N] = A[M][K] * B[N][K]^T, all 4096, A/B bf16 row-major, C fp32.
// 256x256 tile, BK=32, 8 waves (2M x 4N), 8x4 16x16x32-bf16 frags/wave.
// Round-8: round-7's register double-buffer (116.5 us, MfmaUtil 51.6%) MINUS
// the two in-iteration scheduling fences:
//   - setprio toggles removed (waves are barrier-lockstep -> nothing to
//     arbitrate, m190; as side-effecting instrs they pinned cluster bounds
//     and stopped the scheduler weaving ds_reads under MFMAs)
//   - LGKM0 full drain removed (compiler auto-inserts counted lgkmcnt for
//     af47->C2 and prefetch->next-C1; LDS WAR is protected by issue-order +
//     the per-tile barrier; landing gated by VMW4 two iters later)
// Pipeline invariants unchanged: stage horizon t+3, steady vmcnt(4), ONE
// barrier per K-tile, 4-buffer 128 KB LDS, period-4 unroll.
// Same zero-conflict XOR swizzle / XCD swizzle / epilogue as rounds 2-7.

#define GLL(SRC, DST)                                                         \
    __builtin_amdgcn_global_load_lds(                                         \
        (const __attribute__((address_space(1))) void*)(SRC),                 \
        (__attribute__((address_space(3))) void*)(DST), 16, 0, 0)

#define STAGE_AB(T, BUF)                                                      \
  do {                                                                        \
    const __bf16* sa_ = gA0 + (size_t)(T) * 32;                               \
    __bf16* da_ = &smem[(BUF) * 16384 + tid * 8];                             \
    GLL(sa_, da_);                                                            \
    GLL(sa_ + (size_t)524288, da_ + 4096);                                    \
    const __bf16* sb_ = gB0 + (size_t)(T) * 32;                               \
    __bf16* db_ = &smem[(BUF) * 16384 + 8192 + tid * 8];                      \
    GLL(sb_, db_);                                                            \
    GLL(sb_ + (size_t)524288, db_ + 4096);                                    \
  } while (0)

#define VMW4  asm volatile("s_waitcnt vmcnt(4)" ::: "memory")
#define VMW0  asm volatile("s_waitcnt vmcnt(0)" ::: "memory")
#define VMWN  ((void)0)

#define LBFR(D, BUF)                                                          \
    _Pragma("unroll") for (int j_ = 0; j_ < 4; ++j_)                          \
        D[j_] = *(const bf16x8*)(smem + (BUF) * 16384 + offB[j_])
#define LA03(D, BUF)                                                          \
    _Pragma("unroll") for (int i_ = 0; i_ < 4; ++i_)                          \
        D[i_] = *(const bf16x8*)(smem + (BUF) * 16384 + offA[i_])
#define LA47(BUF)                                                             \
    _Pragma("unroll") for (int i_ = 0; i_ < 4; ++i_)                          \
        af47[i_] = *(const bf16x8*)(smem + (BUF) * 16384 + offA[4 + i_])

#define MFMA_C1(CA, CB)                                                       \
    _Pragma("unroll") for (int i_ = 0; i_ < 4; ++i_)                          \
        _Pragma("unroll") for (int j_ = 0; j_ < 4; ++j_)                      \
            acc[i_][j_] = __builtin_amdgcn_mfma_f32_16x16x32_bf16(            \
                CA[i_], CB[j_], acc[i_][j_], 0, 0, 0)
#define MFMA_C2(CB)                                                           \
    _Pragma("unroll") for (int i_ = 0; i_ < 4; ++i_)                          \
        _Pragma("unroll") for (int j_ = 0; j_ < 4; ++j_)                      \
            acc[4 + i_][j_] = __builtin_amdgcn_mfma_f32_16x16x32_bf16(        \
                af47[i_], CB[j_], acc[4 + i_][j_], 0, 0, 0)

// one K-tile: stage(T+3) | LA47(T) | MFMA rows0-3 | prefetch(T+1) | MFMA rows4-7
#define ITER(T, BUFC, BUFN, CB, CA, NB, NA, DOSTAGE, SBUF, VMW, DOBAR)        \
  do {                                                                        \
    if (DOSTAGE) STAGE_AB((T) + 3, SBUF);                                     \
    LA47(BUFC);                                                               \
    MFMA_C1(CA, CB);                                                          \
    LBFR(NB, BUFN);                                                           \
    LA03(NA, BUFN);                                                           \
    MFMA_C2(CB);                                                              \
    VMW;                                                                      \
    if (DOBAR) __builtin_amdgcn_s_barrier();                                  \
  } while (0)

__global__ __launch_bounds__(512, 2) void gemm_bt_kernel(
    const __bf16* __restrict__ A,
    const __bf16* __restrict__ B,
    float* __restrict__ C) {
    __shared__ __bf16 smem[4 * 16384];   // 128 KB: 4 bufs x (A 8192 | B 8192)

    const int tid   = threadIdx.x;
    const int lane  = tid & 63;
    const int wv    = tid >> 6;
    const int wm    = wv >> 2;           // 0..1  -> 128 M-rows each
    const int wn    = wv & 3;            // 0..3  -> 64 N-cols each
    const int row16 = lane & 15;
    const int quad  = lane >> 4;

    // bijective XCD swizzle: 256 blocks, 8 XCDs, 32 contiguous tiles/XCD
    const int swz = (blockIdx.x & 7) * 32 + (blockIdx.x >> 3);
    const int bm  = (swz >> 4) * 256;
    const int bn  = (swz & 15) * 256;

    // staging: 512 thr x 16B = 8 KB = 128 rows of 64 B; 2 issues per matrix.
    // slot p holds pre-swizzle chunk q = p ^ ((row>>1)&3)  (inverse == itself)
    const int sr = tid >> 2;                       // local row 0..127
    const int sq = (tid & 3) ^ ((sr >> 1) & 3);    // source 16B-chunk
    const __bf16* gA0 = A + (size_t)(bm + sr) * 4096 + sq * 8;
    const __bf16* gB0 = B + (size_t)(bn + sr) * 4096 + sq * 8;

    // ds_read element offsets (per-lane, constant across tiles)
    int offA[8], offB[4];
#pragma unroll
    for (int i = 0; i < 8; ++i) {
        const int ra = wm * 128 + i * 16 + row16;
        offA[i] = ra * 32 + ((quad ^ ((ra >> 1) & 3)) * 8);
    }
#pragma unroll
    for (int j = 0; j < 4; ++j) {
        const int rb = wn * 64 + j * 16 + row16;
        offB[j] = 8192 + rb * 32 + ((quad ^ ((rb >> 1) & 3)) * 8);
    }

    f32x4  acc[8][4] = {};
    bf16x8 bfr0[4], a0_[4], bfr1[4], a1_[4], af47[4];

    // prologue: stage tiles 0..2 into bufs 0..2; wait tiles 0,1; preload set0
    STAGE_AB(0, 0); STAGE_AB(1, 1); STAGE_AB(2, 2);
    VMW4;                                   // tiles 0,1 landed (tile 2 in flight)
    __builtin_amdgcn_s_barrier();
    LBFR(bfr0, 0);
    LA03(a0_, 0);

    // main: 31 chunks x 4 iters = tiles 0..123 (buffer %4 compile-time)
    for (int c = 0; c < 31; ++c) {
        const int tb = c * 4;
        ITER(tb + 0, 0, 1, bfr0, a0_, bfr1, a1_, 1, 3, VMW4, 1);
        ITER(tb + 1, 1, 2, bfr1, a1_, bfr0, a0_, 1, 0, VMW4, 1);
        ITER(tb + 2, 2, 3, bfr0, a0_, bfr1, a1_, 1, 1, VMW4, 1);
        ITER(tb + 3, 3, 0, bfr1, a1_, bfr0, a0_, 1, 2, VMW4, 1);
    }
    // tail: tiles 124..127 (last stage = tile 127 at iter 124; drain waits)
    ITER(124, 0, 1, bfr0, a0_, bfr1, a1_, 1, 3, VMW4, 1);
    ITER(125, 1, 2, bfr1, a1_, bfr0, a0_, 0, 0, VMW0, 1);
    ITER(126, 2, 3, bfr0, a0_, bfr1, a1_, 0, 0, VMWN, 0);
    // iter 127: MFMA only (set1 frags loaded at iter 126; af47 from buf 3)
    LA47(3);
    MFMA_C1(a1_, bfr1);
    MFMA_C2(bfr1);

#pragma unroll
    for (int i = 0; i < 8; ++i) {
        const int rbase = bm + wm * 128 + i * 16 + quad * 4;
#pragma unroll
        for (int j = 0; j < 4; ++j) {
            const int col = bn + wn * 64 + j * 16 + row16;
#pragma unroll
            for (int r = 0; r < 4; ++r)
                C[(size_t)(rbase + r) * 4096 + col] = acc[i][j][r];
        }
    }
}

extern "C" void kernel_launch(void* const* d_in, const int* in_sizes, int n_in,
                              void* d_out, int out_size, void* d_ws, size_t ws_size,
                              hipStream_t stream) {
    const float* x    = (const float*)d_in[0];
    const float* vals = (const float*)d_in[1];
    const int*   iin  = (const int*)d_in[2];
    const int*   iout = (const int*)d_in[3];
    float*       C    = (float*)d_out;
    const int    nnz  = in_sizes[1];

    // workspace: Wb 32MB | Xb 32MB | cellcnt 4KB  = 64 MB; bkt lives in d_out
    char*   ws      = (char*)d_ws;
    __bf16* Wb      = (__bf16*)ws;
    __bf16* Xb      = (__bf16*)(ws + ((size_t)32 << 20));
    int*    cellcnt = (int*)(ws + ((size_t)64 << 20));
    uint2*  bkt     = (uint2*)d_out;   // 1024 cells x 8192 cap x 8 B = 64 MB

    zero_kernel<<<4, 256, 0, stream>>>(cellcnt);
    scatres_kernel<<<NBLK, 512, 0, stream>>>(vals, iin, iout, cellcnt, bkt, nnz);
    accum_kernel<<<NCELL, 512, 0, stream>>>(bkt, cellcnt, Wb, (const f32x4*)x, (bf16x8*)Xb);
    gemm_bt_kernel<<<256, 512, 0, stream>>>(Xb, Wb, C);
}